// Round 1
// baseline (2086.789 us; speedup 1.0000x reference)
//
#include <hip/hip_runtime.h>
#include <hip/hip_bf16.h>
#include <cstdint>

constexpr int kB = 16;
constexpr int kL = 64;
constexpr int kD = 768;
constexpr int kE = 100000;
constexpr int kR = 200;
constexpr int kT = 1000000;
constexpr size_t kEB = (size_t)kE * 16;

// ---------------- transpose heads & entity_range into [E,16] ----------------
__global__ void k_transpose(const float* __restrict__ heads, const float* __restrict__ er,
                            float* __restrict__ headsT, float* __restrict__ erT) {
    int e = blockIdx.x * blockDim.x + threadIdx.x;
    int st = gridDim.x * blockDim.x;
    for (; e < kE; e += st) {
        float h[16], r[16];
#pragma unroll
        for (int b = 0; b < 16; b++) {
            h[b] = heads[(size_t)b * kE + e];
            r[b] = er[(size_t)b * kE + e];
        }
#pragma unroll
        for (int c = 0; c < 4; c++) {
            *(float4*)&headsT[(size_t)e * 16 + c * 4] = make_float4(h[c*4], h[c*4+1], h[c*4+2], h[c*4+3]);
            *(float4*)&erT[(size_t)e * 16 + c * 4]    = make_float4(r[c*4], r[c*4+1], r[c*4+2], r[c*4+3]);
        }
    }
}

// ---------------- zero init ----------------
__global__ void k_zero(float* __restrict__ esc, int* __restrict__ cnt,
                       unsigned* __restrict__ rmax, float* __restrict__ ssum,
                       float* __restrict__ hsum) {
    size_t i = (size_t)blockIdx.x * blockDim.x + threadIdx.x;
    size_t st = (size_t)gridDim.x * blockDim.x;
    for (size_t j = i; j < kEB; j += st) esc[j] = 0.f;
    for (size_t j = i; j < kE; j += st) cnt[j] = 0;
    if (i < 96) { rmax[i] = 0u; ssum[i] = 0.f; }
    if (i < 16) hsum[i] = 0.f;
}

// ---------------- CSR build ----------------
__global__ void k_hist(const int* __restrict__ obj, int* __restrict__ cnt) {
    int i = blockIdx.x * blockDim.x + threadIdx.x;
    int st = gridDim.x * blockDim.x;
    for (; i < kT; i += st) atomicAdd(&cnt[obj[i]], 1);
}

__global__ void k_scan1(const int* __restrict__ cnt, int* __restrict__ row, int* __restrict__ bsum) {
    __shared__ int s[512];
    int o = blockIdx.x * 512 + threadIdx.x;
    int v = (o < kE) ? cnt[o] : 0;
    s[threadIdx.x] = v;
    __syncthreads();
    for (int off = 1; off < 512; off <<= 1) {
        int t = (threadIdx.x >= off) ? s[threadIdx.x - off] : 0;
        __syncthreads();
        s[threadIdx.x] += t;
        __syncthreads();
    }
    if (o < kE) row[o + 1] = s[threadIdx.x];   // block-local inclusive
    if (threadIdx.x == 511) bsum[blockIdx.x] = s[511];
}

__global__ void k_scan2(int* __restrict__ bsum, int nb) {
    if (blockIdx.x == 0 && threadIdx.x == 0) {
        int acc = 0;
        for (int i = 0; i < nb; i++) { int v = bsum[i]; bsum[i] = acc; acc += v; }
    }
}

__global__ void k_scan3(const int* __restrict__ cnt, int* __restrict__ row,
                        int* __restrict__ fill, const int* __restrict__ bsum) {
    int o = blockIdx.x * blockDim.x + threadIdx.x;
    if (o == 0) row[0] = 0;
    if (o < kE) {
        int incl = row[o + 1] + bsum[o / 512];
        row[o + 1] = incl;
        fill[o] = incl - cnt[o];
    }
}

__global__ void k_scatter(const int* __restrict__ subj, const int* __restrict__ rel,
                          const int* __restrict__ obj, int* __restrict__ fill,
                          int2* __restrict__ sr) {
    int i = blockIdx.x * blockDim.x + threadIdx.x;
    int st = gridDim.x * blockDim.x;
    for (; i < kT; i += st) {
        int o = obj[i];
        int p = atomicAdd(&fill[o], 1);
        sr[p] = make_int2(subj[i], rel[i]);
    }
}

// ---------------- small dense: qem (i=0) and cq (i=1..6) ----------------
__global__ void k_dense(const float* __restrict__ q, const float* __restrict__ mw,
                        const float* __restrict__ mb, const float* __restrict__ sw,
                        const float* __restrict__ sb, float* __restrict__ cq) {
    int d = blockIdx.x * blockDim.x + threadIdx.x;
    int b = blockIdx.y;
    int i = blockIdx.z;          // 0 = match, 1..6 = steps
    if (d >= kD) return;
    const float* W    = (i == 0) ? mw : sw + (size_t)(i - 1) * kD * kD;
    const float* bias = (i == 0) ? mb : sb + (size_t)(i - 1) * kD;
    const float* qr   = q + (size_t)b * kD;
    float acc = bias[d];
#pragma unroll 8
    for (int k = 0; k < kD; k++) acc += qr[k] * W[(size_t)k * kD + d];
    cq[((size_t)i * kB + b) * kD + d] = (i == 0) ? acc : tanhf(acc);
}

// ---------------- hop attention ----------------
__global__ void k_hop(const float* __restrict__ q, const float* __restrict__ hw,
                      const float* __restrict__ hb, float* __restrict__ hop) {
    int t = threadIdx.x;
    if (t >= 32) return;
    int w = t / 16, b = t % 16;
    float lg[3];
    for (int s = 0; s < 3; s++) {
        float a = hb[w * 3 + s];
        for (int d = 0; d < kD; d++) a += q[(size_t)b * kD + d] * hw[((size_t)w * kD + d) * 3 + s];
        lg[s] = a;
    }
    float mx = fmaxf(lg[0], fmaxf(lg[1], lg[2]));
    float e0 = expf(lg[0] - mx), e1 = expf(lg[1] - mx), e2 = expf(lg[2] - mx);
    float z = e0 + e1 + e2;
    hop[(w * 16 + b) * 3 + 0] = e0 / z;
    hop[(w * 16 + b) * 3 + 1] = e1 / z;
    hop[(w * 16 + b) * 3 + 2] = e2 / z;
}

// ---------------- per-step context + rel distribution -> wr_T ----------------
__global__ void k_ctx(const float* __restrict__ cq, const float* __restrict__ qwh,
                      const int* __restrict__ mask, const float* __restrict__ rw,
                      const float* __restrict__ rb, const float* __restrict__ rimp,
                      const float* __restrict__ temp, float* __restrict__ wrT) {
    int i = blockIdx.x;     // step index 0..5
    int b = blockIdx.y;     // batch
    int w = i / 3;
    __shared__ float red[64][4];
    __shared__ float lgs[64];
    __shared__ float dist[64];
    __shared__ float ctx[768];
    __shared__ float rl[200];
    const float* c  = cq + ((size_t)(i + 1) * kB + b) * kD;
    const float* qh = qwh + (size_t)b * kL * kD;
    int tid = threadIdx.x;
    int l = tid >> 2, part = tid & 3;
    float acc = 0.f;
    for (int d = part * 192; d < part * 192 + 192; d++) acc += c[d] * qh[(size_t)l * kD + d];
    red[l][part] = acc;
    __syncthreads();
    if (tid < 64) lgs[tid] = (red[tid][0] + red[tid][1] + red[tid][2] + red[tid][3]) / temp[0];
    __syncthreads();
    if (tid == 0) {
        float mx = -1e30f;
        for (int j = 0; j < 64; j++) mx = fmaxf(mx, lgs[j]);
        float z = 0.f;
        for (int j = 0; j < 64; j++) { float e = expf(lgs[j] - mx); lgs[j] = e; z += e; }
        float s = 0.f;
        for (int j = 0; j < 64; j++) { float p = lgs[j] / z * (float)mask[b * kL + j]; lgs[j] = p; s += p; }
        float inv = 1.0f / (s + 1e-6f);
        for (int j = 0; j < 64; j++) dist[j] = lgs[j] * inv;
    }
    __syncthreads();
    for (int d = tid; d < kD; d += 256) {
        float a = 0.f;
        for (int j = 0; j < 64; j++) a += dist[j] * qh[(size_t)j * kD + d];
        ctx[d] = a;
    }
    __syncthreads();
    if (tid < kR) {
        float a = rb[w * kR + tid];
        const float* Wr = rw + (size_t)w * kD * kR;
        for (int d = 0; d < kD; d++) a += ctx[d] * Wr[(size_t)d * kR + tid];
        rl[tid] = a;
    }
    __syncthreads();
    if (tid == 0) {
        float mx = -1e30f;
        for (int r = 0; r < kR; r++) mx = fmaxf(mx, rl[r]);
        float z = 0.f;
        for (int r = 0; r < kR; r++) { float e = expf(rl[r] - mx); rl[r] = e; z += e; }
        float inv = 1.0f / z;
        for (int r = 0; r < kR; r++) rl[r] *= inv;
    }
    __syncthreads();
    if (tid < kR) wrT[((size_t)i * kR + tid) * 16 + b] = rl[tid] * rimp[tid];
}

// ---------------- direct matching: sigmoid(qem . emb_e / sqrt(D)) ----------------
__global__ void __launch_bounds__(256) k_direct(const float* __restrict__ emb,
                                                const float* __restrict__ cq,
                                                float* __restrict__ directT) {
    __shared__ __align__(16) float q[16 * 772];   // padded stride 772 (4-bank step, 2-way = free)
    for (int idx = threadIdx.x; idx < 16 * 768; idx += 256) {
        int b = idx / 768, d = idx - b * 768;
        q[b * 772 + d] = cq[idx];
    }
    __syncthreads();
    const float invs = 0.03608439182435161f; // 1/sqrt(768)
    int lane = threadIdx.x & 63;
    int b = lane & 15;
    int es = lane >> 4;                     // 0..3
    int wave_g = (blockIdx.x * 256 + threadIdx.x) >> 6;
    int nwaves = (gridDim.x * 256) >> 6;
    const int nchunk = kE / 16;             // E % 16 == 0
    const float4* qb = (const float4*)(q + b * 772);
    for (int c = wave_g; c < nchunk; c += nwaves) {
        int e0 = c * 16;
        const float4* ep[4];
#pragma unroll
        for (int g = 0; g < 4; g++) ep[g] = (const float4*)(emb + (size_t)(e0 + es + 4 * g) * kD);
        float acc[4] = {0.f, 0.f, 0.f, 0.f};
#pragma unroll 4
        for (int k4 = 0; k4 < 192; k4++) {
            float4 qv = qb[k4];
#pragma unroll
            for (int g = 0; g < 4; g++) {
                float4 ev = ep[g][k4];
                acc[g] += ev.x * qv.x + ev.y * qv.y + ev.z * qv.z + ev.w * qv.w;
            }
        }
#pragma unroll
        for (int g = 0; g < 4; g++) {
            int e = e0 + es + 4 * g;
            directT[(size_t)e * 16 + b] = 1.0f / (1.0f + expf(-acc[g] * invs));
        }
    }
}

// ---------------- enhanced pre-norm + row sums ----------------
__global__ void k_enh0(const float* __restrict__ headsT, const float* __restrict__ directT,
                       float* __restrict__ enhT, float* __restrict__ hsum) {
    __shared__ float ls[16];
    if (threadIdx.x < 16) ls[threadIdx.x] = 0.f;
    __syncthreads();
    float s[16];
#pragma unroll
    for (int b = 0; b < 16; b++) s[b] = 0.f;
    int e = blockIdx.x * blockDim.x + threadIdx.x;
    int st = gridDim.x * blockDim.x;
    for (; e < kE; e += st) {
        size_t base = (size_t)e * 16;
#pragma unroll
        for (int b = 0; b < 16; b++) {
            float v = headsT[base + b] * (1.0f + 0.3f * directT[base + b]);
            enhT[base + b] = v;
            s[b] += v;
        }
    }
#pragma unroll
    for (int b = 0; b < 16; b++) atomicAdd(&ls[b], s[b]);
    __syncthreads();
    if (threadIdx.x < 16) atomicAdd(&hsum[threadIdx.x], ls[threadIdx.x]);
}

__global__ void k_enhnorm(float* __restrict__ enhT, const float* __restrict__ hsum) {
    size_t i = (size_t)blockIdx.x * blockDim.x + threadIdx.x;
    size_t st = (size_t)gridDim.x * blockDim.x;
    for (size_t j = i; j < kEB; j += st) {
        float s = hsum[j & 15];
        enhT[j] /= (s > 0.f ? s : 1.0f);
    }
}

// ---------------- follow: CSR gather, clip, row max ----------------
__global__ void __launch_bounds__(256) k_follow(const float* __restrict__ srcT,
                                                const float* __restrict__ wrT,
                                                const int* __restrict__ row,
                                                const int2* __restrict__ sr,
                                                float* __restrict__ resT,
                                                unsigned* __restrict__ rmax) {
    __shared__ float wrs[kR * 16];
    for (int idx = threadIdx.x; idx < kR * 16; idx += 256) wrs[idx] = wrT[idx];
    __syncthreads();
    int lane = threadIdx.x & 63;
    int b = lane & 15;
    float vmax = 0.f;
    int slot = (blockIdx.x * 256 + threadIdx.x) >> 4;
    int nslots = (gridDim.x * 256) >> 4;
    for (int o = slot; o < kE; o += nslots) {
        float acc = 0.f;
        int j0 = row[o], j1 = row[o + 1];
        for (int j = j0; j < j1; j++) {
            int2 e2 = sr[j];
            acc += srcT[(size_t)e2.x * 16 + b] * wrs[e2.y * 16 + b];
        }
        acc = fminf(fmaxf(acc, 0.f), 1.0f);
        resT[(size_t)o * 16 + b] = acc;
        vmax = fmaxf(vmax, acc);
    }
    vmax = fmaxf(vmax, __shfl_xor(vmax, 32));
    vmax = fmaxf(vmax, __shfl_xor(vmax, 16));
    if (lane < 16) atomicMax(&rmax[b], __float_as_uint(vmax));
}

// ---------------- combine: /max, residual, *entity_range, row sums ----------------
__global__ void k_combine(float* __restrict__ resT, const float* __restrict__ AT,
                          const float* __restrict__ erT, const unsigned* __restrict__ rmax,
                          float* __restrict__ ssum, int has_res) {
    __shared__ float ls[16];
    if (threadIdx.x < 16) ls[threadIdx.x] = 0.f;
    __syncthreads();
    float minv[16];
#pragma unroll
    for (int b = 0; b < 16; b++) {
        float m = __uint_as_float(rmax[b]);
        minv[b] = (m > 0.f) ? (1.0f / m) : 1.0f;
    }
    float s[16];
#pragma unroll
    for (int b = 0; b < 16; b++) s[b] = 0.f;
    int e = blockIdx.x * blockDim.x + threadIdx.x;
    int st = gridDim.x * blockDim.x;
    for (; e < kE; e += st) {
        size_t base = (size_t)e * 16;
#pragma unroll
        for (int b = 0; b < 16; b++) {
            float v = resT[base + b] * minv[b];
            if (has_res) v = 0.7f * v + 0.3f * AT[base + b];
            float u = v * erT[base + b];
            resT[base + b] = u;
            s[b] += u;
        }
    }
#pragma unroll
    for (int b = 0; b < 16; b++) atomicAdd(&ls[b], s[b]);
    __syncthreads();
    if (threadIdx.x < 16) atomicAdd(&ssum[threadIdx.x], ls[threadIdx.x]);
}

// ---------------- normalize + accumulate e_score ----------------
__global__ void k_normacc(const float* __restrict__ resU, float* __restrict__ AT,
                          float* __restrict__ escT, const float* __restrict__ directT,
                          const float* __restrict__ ssum, const float* __restrict__ hop,
                          int t, int way0) {
    float sinv[16], hc[16];
#pragma unroll
    for (int b = 0; b < 16; b++) {
        float s = ssum[b];
        sinv[b] = (s > 0.f) ? (1.0f / s) : 1.0f;
        hc[b] = hop[b * 3 + t];
    }
    int e = blockIdx.x * blockDim.x + threadIdx.x;
    int st = gridDim.x * blockDim.x;
    for (; e < kE; e += st) {
        size_t base = (size_t)e * 16;
#pragma unroll
        for (int b = 0; b < 16; b++) {
            float last = resU[base + b] * sinv[b];
            AT[base + b] = last;
            float scale = way0 ? (1.0f + 0.15f * directT[base + b]) : 1.0f;
            escT[base + b] += hc[b] * last * scale;
        }
    }
}

// ---------------- final transpose to [B,E] ----------------
__global__ void k_final(const float* __restrict__ escT, float* __restrict__ out) {
    int b = blockIdx.y;
    int e = blockIdx.x * blockDim.x + threadIdx.x;
    int st = gridDim.x * blockDim.x;
    for (; e < kE; e += st) out[(size_t)b * kE + e] = escT[(size_t)e * 16 + b];
}

extern "C" void kernel_launch(void* const* d_in, const int* in_sizes, int n_in,
                              void* d_out, int out_size, void* d_ws, size_t ws_size,
                              hipStream_t stream) {
    const float* heads   = (const float*)d_in[0];
    const float* qemb    = (const float*)d_in[1];
    const float* qwh     = (const float*)d_in[2];
    const int*   amask   = (const int*)d_in[3];
    const float* erange  = (const float*)d_in[4];
    const int*   subj    = (const int*)d_in[5];
    const int*   rel     = (const int*)d_in[6];
    const int*   obj     = (const int*)d_in[7];
    const float* rimp    = (const float*)d_in[8];
    const float* emb     = (const float*)d_in[9];
    const float* mw      = (const float*)d_in[10];
    const float* mb      = (const float*)d_in[11];
    const float* sw      = (const float*)d_in[12];
    const float* sb      = (const float*)d_in[13];
    const float* rw      = (const float*)d_in[14];
    const float* rb      = (const float*)d_in[15];
    const float* hw      = (const float*)d_in[16];
    const float* hb      = (const float*)d_in[17];
    const float* temp    = (const float*)d_in[18];
    float* out = (float*)d_out;

    // workspace layout
    float* base = (float*)d_ws;
    float* directT = base;
    float* headsT  = directT + kEB;
    float* erT     = headsT + kEB;
    float* enhT    = erT + kEB;
    float* AT      = enhT + kEB;
    float* resT    = AT + kEB;
    float* escT    = resT + kEB;
    float* cq      = escT + kEB;              // 7*16*768
    float* wrT     = cq + (size_t)7 * 16 * 768; // 6*200*16
    float* hop     = wrT + (size_t)6 * kR * 16; // 96
    float* hsum    = hop + 96;                // 16
    float* ssum    = hsum + 16;               // 96
    unsigned* rmax = (unsigned*)(ssum + 96);  // 96
    int* cnt       = (int*)(rmax + 96);       // E
    int* row       = cnt + kE;                // E+1
    int* fill      = row + kE + 1;            // E
    int* bsum      = fill + kE;               // 256
    int2* sr = (int2*)(((uintptr_t)(bsum + 256) + 255) & ~(uintptr_t)255);

    k_transpose<<<256, 256, 0, stream>>>(heads, erange, headsT, erT);
    k_zero<<<512, 256, 0, stream>>>(escT, cnt, rmax, ssum, hsum);
    k_hist<<<512, 256, 0, stream>>>(obj, cnt);
    const int nb = (kE + 511) / 512;  // 196
    k_scan1<<<nb, 512, 0, stream>>>(cnt, row, bsum);
    k_scan2<<<1, 64, 0, stream>>>(bsum, nb);
    k_scan3<<<(kE + 255) / 256, 256, 0, stream>>>(cnt, row, fill, bsum);
    k_scatter<<<512, 256, 0, stream>>>(subj, rel, obj, fill, sr);

    k_dense<<<dim3(3, 16, 7), 256, 0, stream>>>(qemb, mw, mb, sw, sb, cq);
    k_hop<<<1, 64, 0, stream>>>(qemb, hw, hb, hop);
    k_ctx<<<dim3(6, 16), 256, 0, stream>>>(cq, qwh, amask, rw, rb, rimp, temp, wrT);

    k_direct<<<768, 256, 0, stream>>>(emb, cq, directT);
    k_enh0<<<256, 256, 0, stream>>>(headsT, directT, enhT, hsum);
    k_enhnorm<<<512, 256, 0, stream>>>(enhT, hsum);

    for (int w = 0; w < 2; w++) {
        for (int t = 0; t < 3; t++) {
            int i = w * 3 + t;
            const float* src = (t == 0) ? enhT : AT;
            k_follow<<<512, 256, 0, stream>>>(src, wrT + (size_t)i * kR * 16, row, sr,
                                              resT, rmax + i * 16);
            k_combine<<<256, 256, 0, stream>>>(resT, AT, erT, rmax + i * 16,
                                               ssum + i * 16, t > 0 ? 1 : 0);
            k_normacc<<<256, 256, 0, stream>>>(resT, AT, escT, directT, ssum + i * 16,
                                               hop + w * 48, t, w == 0 ? 1 : 0);
        }
    }
    k_final<<<dim3(128, 16), 256, 0, stream>>>(escT, out);
}

// Round 2
// 1823.135 us; speedup vs baseline: 1.1446x; 1.1446x over previous
//
#include <hip/hip_runtime.h>
#include <hip/hip_bf16.h>
#include <cstdint>

constexpr int kB = 16;
constexpr int kL = 64;
constexpr int kD = 768;
constexpr int kE = 100000;
constexpr int kR = 200;
constexpr int kT = 1000000;
constexpr size_t kEB = (size_t)kE * 16;

// ---------------- init: transpose heads/entity_range to [E,16], zero state ----------------
__global__ void k_init(const float* __restrict__ heads, const float* __restrict__ er,
                       float* __restrict__ headsT, float* __restrict__ erT,
                       float* __restrict__ escT, int* __restrict__ cnt,
                       unsigned* __restrict__ rmax, float* __restrict__ ssum,
                       float* __restrict__ hsum) {
    int e = blockIdx.x * blockDim.x + threadIdx.x;
    int st = gridDim.x * blockDim.x;
    if (e < 96) { rmax[e] = 0u; ssum[e] = 0.f; }
    if (e < 16) hsum[e] = 0.f;
    for (; e < kE; e += st) {
        cnt[e] = 0;
        float h[16], r[16];
#pragma unroll
        for (int b = 0; b < 16; b++) {
            h[b] = heads[(size_t)b * kE + e];
            r[b] = er[(size_t)b * kE + e];
        }
#pragma unroll
        for (int c = 0; c < 4; c++) {
            *(float4*)&headsT[(size_t)e * 16 + c * 4] = make_float4(h[c*4], h[c*4+1], h[c*4+2], h[c*4+3]);
            *(float4*)&erT[(size_t)e * 16 + c * 4]    = make_float4(r[c*4], r[c*4+1], r[c*4+2], r[c*4+3]);
            *(float4*)&escT[(size_t)e * 16 + c * 4]   = make_float4(0.f, 0.f, 0.f, 0.f);
        }
    }
}

// ---------------- CSR build ----------------
__global__ void k_hist(const int* __restrict__ obj, int* __restrict__ cnt) {
    int i = blockIdx.x * blockDim.x + threadIdx.x;
    int st = gridDim.x * blockDim.x;
    for (; i < kT; i += st) atomicAdd(&cnt[obj[i]], 1);
}

__global__ void k_scan1(const int* __restrict__ cnt, int* __restrict__ row, int* __restrict__ bsum) {
    __shared__ int s[512];
    int o = blockIdx.x * 512 + threadIdx.x;
    int v = (o < kE) ? cnt[o] : 0;
    s[threadIdx.x] = v;
    __syncthreads();
    for (int off = 1; off < 512; off <<= 1) {
        int t = (threadIdx.x >= off) ? s[threadIdx.x - off] : 0;
        __syncthreads();
        s[threadIdx.x] += t;
        __syncthreads();
    }
    if (o < kE) row[o + 1] = s[threadIdx.x];   // block-local inclusive
    if (threadIdx.x == 511) bsum[blockIdx.x] = s[511];
}

// parallel single-block exclusive scan over block sums (nb <= 256)
__global__ void k_scan2(int* __restrict__ bsum, int nb) {
    __shared__ int s[256];
    int t = threadIdx.x;
    int v = (t < nb) ? bsum[t] : 0;
    s[t] = v;
    __syncthreads();
    for (int off = 1; off < 256; off <<= 1) {
        int x = (t >= off) ? s[t - off] : 0;
        __syncthreads();
        s[t] += x;
        __syncthreads();
    }
    if (t < nb) bsum[t] = s[t] - v;   // exclusive
}

__global__ void k_scan3(const int* __restrict__ cnt, int* __restrict__ row,
                        int* __restrict__ fill, const int* __restrict__ bsum) {
    int o = blockIdx.x * blockDim.x + threadIdx.x;
    if (o == 0) row[0] = 0;
    if (o < kE) {
        int incl = row[o + 1] + bsum[o / 512];
        row[o + 1] = incl;
        fill[o] = incl - cnt[o];
    }
}

__global__ void k_scatter(const int* __restrict__ subj, const int* __restrict__ rel,
                          const int* __restrict__ obj, int* __restrict__ fill,
                          int2* __restrict__ sr) {
    int i = blockIdx.x * blockDim.x + threadIdx.x;
    int st = gridDim.x * blockDim.x;
    for (; i < kT; i += st) {
        int o = obj[i];
        int p = atomicAdd(&fill[o], 1);
        sr[p] = make_int2(subj[i], rel[i]);
    }
}

// ---------------- small dense: qem (i=0) and cq (i=1..6) ----------------
__global__ void k_dense(const float* __restrict__ q, const float* __restrict__ mw,
                        const float* __restrict__ mb, const float* __restrict__ sw,
                        const float* __restrict__ sb, float* __restrict__ cq) {
    int d = blockIdx.x * blockDim.x + threadIdx.x;
    int b = blockIdx.y;
    int i = blockIdx.z;          // 0 = match, 1..6 = steps
    if (d >= kD) return;
    const float* W    = (i == 0) ? mw : sw + (size_t)(i - 1) * kD * kD;
    const float* bias = (i == 0) ? mb : sb + (size_t)(i - 1) * kD;
    const float* qr   = q + (size_t)b * kD;
    float acc = bias[d];
#pragma unroll 8
    for (int k = 0; k < kD; k++) acc += qr[k] * W[(size_t)k * kD + d];
    cq[((size_t)i * kB + b) * kD + d] = (i == 0) ? acc : tanhf(acc);
}

// ---------------- hop attention ----------------
__global__ void k_hop(const float* __restrict__ q, const float* __restrict__ hw,
                      const float* __restrict__ hb, float* __restrict__ hop) {
    int t = threadIdx.x;
    if (t >= 32) return;
    int w = t / 16, b = t % 16;
    float lg[3];
    for (int s = 0; s < 3; s++) {
        float a = hb[w * 3 + s];
        for (int d = 0; d < kD; d++) a += q[(size_t)b * kD + d] * hw[((size_t)w * kD + d) * 3 + s];
        lg[s] = a;
    }
    float mx = fmaxf(lg[0], fmaxf(lg[1], lg[2]));
    float e0 = expf(lg[0] - mx), e1 = expf(lg[1] - mx), e2 = expf(lg[2] - mx);
    float z = e0 + e1 + e2;
    hop[(w * 16 + b) * 3 + 0] = e0 / z;
    hop[(w * 16 + b) * 3 + 1] = e1 / z;
    hop[(w * 16 + b) * 3 + 2] = e2 / z;
}

// ---------------- per-step context + rel distribution -> wr_T ----------------
__global__ void k_ctx(const float* __restrict__ cq, const float* __restrict__ qwh,
                      const int* __restrict__ mask, const float* __restrict__ rw,
                      const float* __restrict__ rb, const float* __restrict__ rimp,
                      const float* __restrict__ temp, float* __restrict__ wrT) {
    int i = blockIdx.x;     // step index 0..5
    int b = blockIdx.y;     // batch
    int w = i / 3;
    __shared__ float red[64][4];
    __shared__ float lgs[64];
    __shared__ float dist[64];
    __shared__ float ctx[768];
    __shared__ float rl[200];
    const float* c  = cq + ((size_t)(i + 1) * kB + b) * kD;
    const float* qh = qwh + (size_t)b * kL * kD;
    int tid = threadIdx.x;
    int l = tid >> 2, part = tid & 3;
    float acc = 0.f;
    for (int d = part * 192; d < part * 192 + 192; d++) acc += c[d] * qh[(size_t)l * kD + d];
    red[l][part] = acc;
    __syncthreads();
    if (tid < 64) lgs[tid] = (red[tid][0] + red[tid][1] + red[tid][2] + red[tid][3]) / temp[0];
    __syncthreads();
    if (tid == 0) {
        float mx = -1e30f;
        for (int j = 0; j < 64; j++) mx = fmaxf(mx, lgs[j]);
        float z = 0.f;
        for (int j = 0; j < 64; j++) { float e = expf(lgs[j] - mx); lgs[j] = e; z += e; }
        float s = 0.f;
        for (int j = 0; j < 64; j++) { float p = lgs[j] / z * (float)mask[b * kL + j]; lgs[j] = p; s += p; }
        float inv = 1.0f / (s + 1e-6f);
        for (int j = 0; j < 64; j++) dist[j] = lgs[j] * inv;
    }
    __syncthreads();
    for (int d = tid; d < kD; d += 256) {
        float a = 0.f;
        for (int j = 0; j < 64; j++) a += dist[j] * qh[(size_t)j * kD + d];
        ctx[d] = a;
    }
    __syncthreads();
    if (tid < kR) {
        float a = rb[w * kR + tid];
        const float* Wr = rw + (size_t)w * kD * kR;
        for (int d = 0; d < kD; d++) a += ctx[d] * Wr[(size_t)d * kR + tid];
        rl[tid] = a;
    }
    __syncthreads();
    if (tid == 0) {
        float mx = -1e30f;
        for (int r = 0; r < kR; r++) mx = fmaxf(mx, rl[r]);
        float z = 0.f;
        for (int r = 0; r < kR; r++) { float e = expf(rl[r] - mx); rl[r] = e; z += e; }
        float inv = 1.0f / z;
        for (int r = 0; r < kR; r++) rl[r] *= inv;
    }
    __syncthreads();
    if (tid < kR) wrT[((size_t)i * kR + tid) * 16 + b] = rl[tid] * rimp[tid];
}

// ---------------- direct matching: one entity per lane, q via scalar loads ----------------
__global__ void __launch_bounds__(256) k_direct(const float* __restrict__ emb,
                                                const float* __restrict__ cq,
                                                float* __restrict__ directT) {
    int e = blockIdx.x * blockDim.x + threadIdx.x;
    if (e >= kE) return;
    const float invs = 0.03608439182435161f; // 1/sqrt(768)
    const float4* er = (const float4*)(emb + (size_t)e * kD);
    float acc[16];
#pragma unroll
    for (int b = 0; b < 16; b++) acc[b] = 0.f;
    for (int k8 = 0; k8 < 24; k8++) {        // 24 * 8 float4 = 768 floats
        float4 ev[8];
#pragma unroll
        for (int u = 0; u < 8; u++) ev[u] = er[k8 * 8 + u];
#pragma unroll
        for (int b = 0; b < 16; b++) {
            const float4* qp = (const float4*)(cq + (size_t)b * kD) + k8 * 8;
#pragma unroll
            for (int u = 0; u < 8; u++) {
                float4 qv = qp[u];   // wave-uniform -> scalar load broadcast
                acc[b] += ev[u].x * qv.x + ev[u].y * qv.y + ev[u].z * qv.z + ev[u].w * qv.w;
            }
        }
    }
#pragma unroll
    for (int b = 0; b < 16; b++) acc[b] = 1.0f / (1.0f + expf(-acc[b] * invs));
#pragma unroll
    for (int c = 0; c < 4; c++)
        *(float4*)&directT[(size_t)e * 16 + c * 4] =
            make_float4(acc[c*4], acc[c*4+1], acc[c*4+2], acc[c*4+3]);
}

// ---------------- enhanced (unnormalized) + row sums ----------------
__global__ void k_enh0(const float* __restrict__ headsT, const float* __restrict__ directT,
                       float* __restrict__ enhT, float* __restrict__ hsum) {
    __shared__ float ls[16];
    if (threadIdx.x < 16) ls[threadIdx.x] = 0.f;
    __syncthreads();
    float s[16];
#pragma unroll
    for (int b = 0; b < 16; b++) s[b] = 0.f;
    int e = blockIdx.x * blockDim.x + threadIdx.x;
    int st = gridDim.x * blockDim.x;
    for (; e < kE; e += st) {
        size_t base = (size_t)e * 16;
#pragma unroll
        for (int b = 0; b < 16; b++) {
            float v = headsT[base + b] * (1.0f + 0.3f * directT[base + b]);
            enhT[base + b] = v;
            s[b] += v;
        }
    }
#pragma unroll
    for (int b = 0; b < 16; b++) atomicAdd(&ls[b], s[b]);
    __syncthreads();
    if (threadIdx.x < 16) atomicAdd(&hsum[threadIdx.x], ls[threadIdx.x]);
}

// ---------------- follow: CSR gather; src row-normalization folded into wr ----------------
__global__ void __launch_bounds__(256) k_follow(const float* __restrict__ srcT,
                                                const float* __restrict__ wrT,
                                                const int* __restrict__ row,
                                                const int2* __restrict__ sr,
                                                float* __restrict__ resT,
                                                unsigned* __restrict__ rmax,
                                                const float* __restrict__ rowsum,
                                                int use_rs) {
    __shared__ float wrs[kR * 16];
    __shared__ float sinv[16];
    if (threadIdx.x < 16) {
        float s = rowsum[threadIdx.x];
        sinv[threadIdx.x] = (use_rs && s > 0.f) ? (1.0f / s) : 1.0f;
    }
    __syncthreads();
    for (int idx = threadIdx.x; idx < kR * 16; idx += 256) wrs[idx] = wrT[idx] * sinv[idx & 15];
    __syncthreads();
    int b = threadIdx.x & 15;
    float vmax = 0.f;
    int slot = (blockIdx.x * 256 + threadIdx.x) >> 4;
    int nslots = (gridDim.x * 256) >> 4;
    for (int o = slot; o < kE; o += nslots) {
        int j0 = row[o], j1 = row[o + 1];
        float a0 = 0.f, a1 = 0.f;
        int j = j0;
        for (; j + 2 <= j1; j += 2) {
            int2 p0 = sr[j], p1 = sr[j + 1];
            a0 += srcT[(size_t)p0.x * 16 + b] * wrs[p0.y * 16 + b];
            a1 += srcT[(size_t)p1.x * 16 + b] * wrs[p1.y * 16 + b];
        }
        if (j < j1) { int2 p = sr[j]; a0 += srcT[(size_t)p.x * 16 + b] * wrs[p.y * 16 + b]; }
        float acc = fminf(fmaxf(a0 + a1, 0.f), 1.0f);
        resT[(size_t)o * 16 + b] = acc;
        vmax = fmaxf(vmax, acc);
    }
    vmax = fmaxf(vmax, __shfl_xor(vmax, 32));
    vmax = fmaxf(vmax, __shfl_xor(vmax, 16));
    if ((threadIdx.x & 63) < 16) atomicMax(&rmax[b], __float_as_uint(vmax));
}

// ---------------- combine: /max, residual, *entity_range, row sums ----------------
__global__ void k_combine(float* __restrict__ resT, const float* __restrict__ AT,
                          const float* __restrict__ erT, const unsigned* __restrict__ rmax,
                          float* __restrict__ ssum, int has_res) {
    __shared__ float ls[16];
    if (threadIdx.x < 16) ls[threadIdx.x] = 0.f;
    __syncthreads();
    float minv[16];
#pragma unroll
    for (int b = 0; b < 16; b++) {
        float m = __uint_as_float(rmax[b]);
        minv[b] = (m > 0.f) ? (1.0f / m) : 1.0f;
    }
    float s[16];
#pragma unroll
    for (int b = 0; b < 16; b++) s[b] = 0.f;
    int e = blockIdx.x * blockDim.x + threadIdx.x;
    int st = gridDim.x * blockDim.x;
    for (; e < kE; e += st) {
        size_t base = (size_t)e * 16;
#pragma unroll
        for (int b = 0; b < 16; b++) {
            float v = resT[base + b] * minv[b];
            if (has_res) v = 0.7f * v + 0.3f * AT[base + b];
            float u = v * erT[base + b];
            resT[base + b] = u;
            s[b] += u;
        }
    }
#pragma unroll
    for (int b = 0; b < 16; b++) atomicAdd(&ls[b], s[b]);
    __syncthreads();
    if (threadIdx.x < 16) atomicAdd(&ssum[threadIdx.x], ls[threadIdx.x]);
}

// ---------------- normalize + accumulate e_score (+ final output fusion) ----------------
__global__ void k_normacc(const float* __restrict__ resU, float* __restrict__ AT,
                          float* __restrict__ escT, const float* __restrict__ directT,
                          const float* __restrict__ ssum, const float* __restrict__ hop,
                          int t, int way0, float* __restrict__ out, int is_last) {
    float sinv[16], hc[16];
#pragma unroll
    for (int b = 0; b < 16; b++) {
        float s = ssum[b];
        sinv[b] = (s > 0.f) ? (1.0f / s) : 1.0f;
        hc[b] = hop[b * 3 + t];
    }
    int e = blockIdx.x * blockDim.x + threadIdx.x;
    int st = gridDim.x * blockDim.x;
    for (; e < kE; e += st) {
        size_t base = (size_t)e * 16;
#pragma unroll
        for (int b = 0; b < 16; b++) {
            float last = resU[base + b] * sinv[b];
            float scale = way0 ? (1.0f + 0.15f * directT[base + b]) : 1.0f;
            float val = escT[base + b] + hc[b] * last * scale;
            if (is_last) {
                out[(size_t)b * kE + e] = val;
            } else {
                AT[base + b] = last;
                escT[base + b] = val;
            }
        }
    }
}

extern "C" void kernel_launch(void* const* d_in, const int* in_sizes, int n_in,
                              void* d_out, int out_size, void* d_ws, size_t ws_size,
                              hipStream_t stream) {
    const float* heads   = (const float*)d_in[0];
    const float* qemb    = (const float*)d_in[1];
    const float* qwh     = (const float*)d_in[2];
    const int*   amask   = (const int*)d_in[3];
    const float* erange  = (const float*)d_in[4];
    const int*   subj    = (const int*)d_in[5];
    const int*   rel     = (const int*)d_in[6];
    const int*   obj     = (const int*)d_in[7];
    const float* rimp    = (const float*)d_in[8];
    const float* emb     = (const float*)d_in[9];
    const float* mw      = (const float*)d_in[10];
    const float* mb      = (const float*)d_in[11];
    const float* sw      = (const float*)d_in[12];
    const float* sb      = (const float*)d_in[13];
    const float* rw      = (const float*)d_in[14];
    const float* rb      = (const float*)d_in[15];
    const float* hw      = (const float*)d_in[16];
    const float* hb      = (const float*)d_in[17];
    const float* temp    = (const float*)d_in[18];
    float* out = (float*)d_out;

    // workspace layout
    float* base = (float*)d_ws;
    float* directT = base;
    float* headsT  = directT + kEB;
    float* erT     = headsT + kEB;
    float* enhT    = erT + kEB;
    float* AT      = enhT + kEB;
    float* resT    = AT + kEB;
    float* escT    = resT + kEB;
    float* cq      = escT + kEB;                // 7*16*768
    float* wrT     = cq + (size_t)7 * 16 * 768; // 6*200*16
    float* hop     = wrT + (size_t)6 * kR * 16; // 96
    float* hsum    = hop + 96;                  // 16
    float* ssum    = hsum + 16;                 // 96
    unsigned* rmax = (unsigned*)(ssum + 96);    // 96
    int* cnt       = (int*)(rmax + 96);         // E
    int* row       = cnt + kE;                  // E+1
    int* fill      = row + kE + 1;              // E
    int* bsum      = fill + kE;                 // 256
    int2* sr = (int2*)(((uintptr_t)(bsum + 256) + 255) & ~(uintptr_t)255);

    k_init<<<256, 256, 0, stream>>>(heads, erange, headsT, erT, escT, cnt, rmax, ssum, hsum);
    k_hist<<<512, 256, 0, stream>>>(obj, cnt);
    const int nb = (kE + 511) / 512;  // 196
    k_scan1<<<nb, 512, 0, stream>>>(cnt, row, bsum);
    k_scan2<<<1, 256, 0, stream>>>(bsum, nb);
    k_scan3<<<(kE + 255) / 256, 256, 0, stream>>>(cnt, row, fill, bsum);
    k_scatter<<<512, 256, 0, stream>>>(subj, rel, obj, fill, sr);

    k_dense<<<dim3(3, 16, 7), 256, 0, stream>>>(qemb, mw, mb, sw, sb, cq);
    k_hop<<<1, 64, 0, stream>>>(qemb, hw, hb, hop);
    k_ctx<<<dim3(6, 16), 256, 0, stream>>>(cq, qwh, amask, rw, rb, rimp, temp, wrT);

    k_direct<<<(kE + 255) / 256, 256, 0, stream>>>(emb, cq, directT);
    k_enh0<<<256, 256, 0, stream>>>(headsT, directT, enhT, hsum);

    for (int w = 0; w < 2; w++) {
        for (int t = 0; t < 3; t++) {
            int i = w * 3 + t;
            const float* src = (t == 0) ? enhT : AT;
            k_follow<<<1024, 256, 0, stream>>>(src, wrT + (size_t)i * kR * 16, row, sr,
                                               resT, rmax + i * 16, hsum, t == 0 ? 1 : 0);
            k_combine<<<256, 256, 0, stream>>>(resT, AT, erT, rmax + i * 16,
                                               ssum + i * 16, t > 0 ? 1 : 0);
            k_normacc<<<256, 256, 0, stream>>>(resT, AT, escT, directT, ssum + i * 16,
                                               hop + w * 48, t, w == 0 ? 1 : 0,
                                               out, (w == 1 && t == 2) ? 1 : 0);
        }
    }
}

// Round 3
// 1452.517 us; speedup vs baseline: 1.4367x; 1.2552x over previous
//
#include <hip/hip_runtime.h>
#include <cstdint>

constexpr int kB = 16;
constexpr int kL = 64;
constexpr int kD = 768;
constexpr int kE = 100000;
constexpr int kR = 200;
constexpr int kT = 1000000;
constexpr size_t kEB = (size_t)kE * 16;
constexpr int kEBq = kE * 4;   // float4 count of an [E,16] array

// ---------------- init: transpose heads/er to [E,16], zero state ----------------
__global__ void __launch_bounds__(256) k_init(const float* __restrict__ heads,
        const float* __restrict__ er, float* __restrict__ headsT, float* __restrict__ erT,
        float* __restrict__ escT, int* __restrict__ cnt, unsigned* __restrict__ rmax,
        float* __restrict__ ssum, float* __restrict__ hsum) {
    int tid = blockIdx.x * blockDim.x + threadIdx.x;
    int gsz = gridDim.x * blockDim.x;
    if (tid < 96) { rmax[tid] = 0u; ssum[tid] = 0.f; }
    if (tid < 16) hsum[tid] = 0.f;
    float4 z4 = make_float4(0.f, 0.f, 0.f, 0.f);
    float4* esc4 = (float4*)escT;
    for (int i = tid; i < kEBq; i += gsz) esc4[i] = z4;
    for (int i = tid; i < kE; i += gsz) cnt[i] = 0;
    const float4* h4 = (const float4*)heads;
    const float4* r4 = (const float4*)er;
    for (int q = tid; q < kE / 4; q += gsz) {
        float hv[16][4], rv[16][4];
#pragma unroll
        for (int b = 0; b < 16; b++) {
            float4 h = h4[b * (kE / 4) + q];
            float4 r = r4[b * (kE / 4) + q];
            hv[b][0] = h.x; hv[b][1] = h.y; hv[b][2] = h.z; hv[b][3] = h.w;
            rv[b][0] = r.x; rv[b][1] = r.y; rv[b][2] = r.z; rv[b][3] = r.w;
        }
        float4* oh = (float4*)headsT + (size_t)q * 16;
        float4* orr = (float4*)erT + (size_t)q * 16;
#pragma unroll
        for (int u = 0; u < 4; u++) {
#pragma unroll
            for (int c = 0; c < 4; c++) {
                oh[u * 4 + c] = make_float4(hv[4*c][u], hv[4*c+1][u], hv[4*c+2][u], hv[4*c+3][u]);
                orr[u * 4 + c] = make_float4(rv[4*c][u], rv[4*c+1][u], rv[4*c+2][u], rv[4*c+3][u]);
            }
        }
    }
}

// ---------------- CSR build ----------------
__global__ void k_hist(const int* __restrict__ obj, int* __restrict__ cnt) {
    int i = blockIdx.x * blockDim.x + threadIdx.x;
    int st = gridDim.x * blockDim.x;
    for (; i < kT; i += st) atomicAdd(&cnt[obj[i]], 1);
}

__global__ void k_scan1(const int* __restrict__ cnt, int* __restrict__ row, int* __restrict__ bsum) {
    __shared__ int s[512];
    int o = blockIdx.x * 512 + threadIdx.x;
    int v = (o < kE) ? cnt[o] : 0;
    s[threadIdx.x] = v;
    __syncthreads();
    for (int off = 1; off < 512; off <<= 1) {
        int t = (threadIdx.x >= off) ? s[threadIdx.x - off] : 0;
        __syncthreads();
        s[threadIdx.x] += t;
        __syncthreads();
    }
    if (o < kE) row[o + 1] = s[threadIdx.x];
    if (threadIdx.x == 511) bsum[blockIdx.x] = s[511];
}

__global__ void k_scan2(int* __restrict__ bsum, int nb) {
    __shared__ int s[256];
    int t = threadIdx.x;
    int v = (t < nb) ? bsum[t] : 0;
    s[t] = v;
    __syncthreads();
    for (int off = 1; off < 256; off <<= 1) {
        int x = (t >= off) ? s[t - off] : 0;
        __syncthreads();
        s[t] += x;
        __syncthreads();
    }
    if (t < nb) bsum[t] = s[t] - v;
}

__global__ void k_scan3(const int* __restrict__ cnt, int* __restrict__ row,
                        int* __restrict__ fill, const int* __restrict__ bsum) {
    int o = blockIdx.x * blockDim.x + threadIdx.x;
    if (o == 0) row[0] = 0;
    if (o < kE) {
        int incl = row[o + 1] + bsum[o / 512];
        row[o + 1] = incl;
        fill[o] = incl - cnt[o];
    }
}

__global__ void k_scatter(const int* __restrict__ subj, const int* __restrict__ rel,
                          const int* __restrict__ obj, int* __restrict__ fill,
                          int2* __restrict__ sr) {
    int i = blockIdx.x * blockDim.x + threadIdx.x;
    int st = gridDim.x * blockDim.x;
    for (; i < kT; i += st) {
        int o = obj[i];
        int p = atomicAdd(&fill[o], 1);
        sr[p] = make_int2(subj[i], rel[i]);
    }
}

// ---------------- small dense: qem (i=0) and cq (i=1..6), float4 over d ----------------
__global__ void __launch_bounds__(192) k_dense(const float* __restrict__ q,
        const float* __restrict__ mw, const float* __restrict__ mb,
        const float* __restrict__ sw, const float* __restrict__ sb,
        float* __restrict__ cq) {
    int tid = threadIdx.x;
    int b = blockIdx.x, i = blockIdx.y;
    const float* W    = (i == 0) ? mw : sw + (size_t)(i - 1) * kD * kD;
    const float* bias = (i == 0) ? mb : sb + (size_t)(i - 1) * kD;
    const float* qr   = q + (size_t)b * kD;
    const float4* W4 = (const float4*)W;
    float4 acc = ((const float4*)bias)[tid];
#pragma unroll 4
    for (int k = 0; k < kD; k++) {
        float qk = qr[k];
        float4 wv = W4[k * 192 + tid];
        acc.x += qk * wv.x; acc.y += qk * wv.y; acc.z += qk * wv.z; acc.w += qk * wv.w;
    }
    if (i > 0) { acc.x = tanhf(acc.x); acc.y = tanhf(acc.y); acc.z = tanhf(acc.z); acc.w = tanhf(acc.w); }
    ((float4*)cq)[((size_t)i * 16 + b) * 192 + tid] = acc;
}

// ---------------- hop attention (layout hopL[(w*3+t)*16+b]) ----------------
__global__ void __launch_bounds__(192) k_hop(const float* __restrict__ q,
        const float* __restrict__ hw, const float* __restrict__ hb,
        float* __restrict__ hopL) {
    int w = blockIdx.x, b = blockIdx.y, t = threadIdx.x;
    __shared__ float red[3][192];
    const float4* q4 = (const float4*)(q + (size_t)b * kD);
    float4 qv = q4[t];
    const float* hp = hw + ((size_t)w * kD + 4 * t) * 3;
    float p[3];
#pragma unroll
    for (int s = 0; s < 3; s++)
        p[s] = qv.x * hp[s] + qv.y * hp[3 + s] + qv.z * hp[6 + s] + qv.w * hp[9 + s];
#pragma unroll
    for (int s = 0; s < 3; s++) red[s][t] = p[s];
    __syncthreads();
    for (int off = 96; off >= 3; off >>= 1) {
        if (t < off) {
#pragma unroll
            for (int s = 0; s < 3; s++) red[s][t] += red[s][t + off];
        }
        __syncthreads();
    }
    if (t == 0) {
        float lg[3];
#pragma unroll
        for (int s = 0; s < 3; s++) lg[s] = red[s][0] + red[s][1] + red[s][2] + hb[w * 3 + s];
        float mx = fmaxf(lg[0], fmaxf(lg[1], lg[2]));
        float e0 = expf(lg[0] - mx), e1 = expf(lg[1] - mx), e2 = expf(lg[2] - mx);
        float z = e0 + e1 + e2;
        hopL[(w * 3 + 0) * 16 + b] = e0 / z;
        hopL[(w * 3 + 1) * 16 + b] = e1 / z;
        hopL[(w * 3 + 2) * 16 + b] = e2 / z;
    }
}

// ---------------- per-step context + rel distribution -> wrT ----------------
__global__ void __launch_bounds__(256) k_ctx(const float* __restrict__ cq,
        const float* __restrict__ qwh, const int* __restrict__ mask,
        const float* __restrict__ rw, const float* __restrict__ rb,
        const float* __restrict__ rimp, const float* __restrict__ temp,
        float* __restrict__ wrT) {
    int i = blockIdx.x, b = blockIdx.y, w = i / 3;
    __shared__ float red[64][4];
    __shared__ float dist[64];
    __shared__ float ctx[768];
    __shared__ float rl[200];
    __shared__ float tbuf[8];
    int tid = threadIdx.x;
    const float4* c4 = (const float4*)(cq + ((size_t)(i + 1) * 16 + b) * kD);
    const float4* qh4 = (const float4*)(qwh + (size_t)b * kL * kD);
    {
        int l = tid >> 2, part = tid & 3;
        float a = 0.f;
        for (int u = 0; u < 48; u++) {
            float4 qv = qh4[l * 192 + part * 48 + u];
            float4 cv = c4[part * 48 + u];
            a += qv.x * cv.x + qv.y * cv.y + qv.z * cv.z + qv.w * cv.w;
        }
        red[l][part] = a;
    }
    __syncthreads();
    if (tid < 64) {
        float lg = (red[tid][0] + red[tid][1] + red[tid][2] + red[tid][3]) / temp[0];
        float mx = lg;
        for (int o = 32; o > 0; o >>= 1) mx = fmaxf(mx, __shfl_xor(mx, o));
        float e = expf(lg - mx);
        float z = e;
        for (int o = 32; o > 0; o >>= 1) z += __shfl_xor(z, o);
        float p = e / z * (float)mask[b * kL + tid];
        float s = p;
        for (int o = 32; o > 0; o >>= 1) s += __shfl_xor(s, o);
        dist[tid] = p / (s + 1e-6f);
    }
    __syncthreads();
    if (tid < 192) {
        float4 a = make_float4(0.f, 0.f, 0.f, 0.f);
        for (int l = 0; l < 64; l++) {
            float dl = dist[l];
            float4 qv = qh4[l * 192 + tid];
            a.x += dl * qv.x; a.y += dl * qv.y; a.z += dl * qv.z; a.w += dl * qv.w;
        }
        ((float4*)ctx)[tid] = a;
    }
    __syncthreads();
    if (tid < kR) {
        float a = rb[w * kR + tid];
        const float* Wr = rw + (size_t)w * kD * kR;
#pragma unroll 4
        for (int d = 0; d < kD; d++) a += ctx[d] * Wr[(size_t)d * kR + tid];
        rl[tid] = a;
    }
    __syncthreads();
    {
        float v = (tid < kR) ? rl[tid] : -1e30f;
        float mx = v;
        for (int o = 32; o > 0; o >>= 1) mx = fmaxf(mx, __shfl_xor(mx, o));
        if ((tid & 63) == 0) tbuf[tid >> 6] = mx;
        __syncthreads();
        mx = fmaxf(fmaxf(tbuf[0], tbuf[1]), fmaxf(tbuf[2], tbuf[3]));
        float e = expf(v - mx);
        float z = e;
        for (int o = 32; o > 0; o >>= 1) z += __shfl_xor(z, o);
        if ((tid & 63) == 0) tbuf[4 + (tid >> 6)] = z;
        __syncthreads();
        z = tbuf[4] + tbuf[5] + tbuf[6] + tbuf[7];
        if (tid < kR) wrT[((size_t)i * kR + tid) * 16 + b] = (e / z) * rimp[tid];
    }
}

// ---------------- direct matching + fused enhanced/hsum epilogue ----------------
__global__ void __launch_bounds__(256) k_direct(const float4* __restrict__ emb4,
        const float4* __restrict__ q4, const float4* __restrict__ headsT4,
        float4* __restrict__ directT4, float4* __restrict__ enhU4,
        float* __restrict__ hsum) {
    __shared__ float4 lds[256 * 13];
    __shared__ float hs[16];
    const int t = threadIdx.x;
    if (t < 16) hs[t] = 0.f;
    const int e0 = blockIdx.x * 128;
    const int ent = t & 127;
    const int half = t >> 7;                 // wave-uniform
    float acc[16];
#pragma unroll
    for (int b = 0; b < 16; b++) acc[b] = 0.f;
    for (int c = 0; c < 8; c++) {
        __syncthreads();
#pragma unroll
        for (int u = 0; u < 12; u++) {
            int l = u * 256 + t;
            int seg = l / 12, part = l - seg * 12;
            int ph = ((seg & 1) << 7) | (seg >> 1);
            int ge = e0 + (seg >> 1);
            float4 v = make_float4(0.f, 0.f, 0.f, 0.f);
            if (ge < kE) v = emb4[(size_t)ge * 192 + (seg & 1) * 96 + c * 12 + part];
            lds[ph * 13 + part] = v;
        }
        __syncthreads();
#pragma unroll
        for (int j = 0; j < 12; j++) {
            float4 ev = lds[t * 13 + j];
            int qk = half * 96 + c * 12 + j;  // wave-uniform -> scalar q loads
#pragma unroll
            for (int b = 0; b < 16; b++) {
                float4 qv = q4[b * 192 + qk];
                acc[b] += ev.x * qv.x + ev.y * qv.y + ev.z * qv.z + ev.w * qv.w;
            }
        }
    }
    __syncthreads();
    float* red = (float*)lds;
    if (half == 1) {
#pragma unroll
        for (int b = 0; b < 16; b++) red[ent * 17 + b] = acc[b];
    }
    __syncthreads();
    if (half == 0) {
        int ge = e0 + ent;
        const float invs = 0.03608439182435161f; // 1/sqrt(768)
        float v[16];
        if (ge < kE) {
            float d[16];
#pragma unroll
            for (int b = 0; b < 16; b++) {
                float x = acc[b] + red[ent * 17 + b];
                d[b] = 1.f / (1.f + expf(-x * invs));
            }
            float4 hq[4];
#pragma unroll
            for (int cc = 0; cc < 4; cc++) {
                directT4[(size_t)ge * 4 + cc] = make_float4(d[4*cc], d[4*cc+1], d[4*cc+2], d[4*cc+3]);
                hq[cc] = headsT4[(size_t)ge * 4 + cc];
            }
#pragma unroll
            for (int cc = 0; cc < 4; cc++) {
                float4 e;
                e.x = hq[cc].x * (1.f + 0.3f * d[4*cc+0]);
                e.y = hq[cc].y * (1.f + 0.3f * d[4*cc+1]);
                e.z = hq[cc].z * (1.f + 0.3f * d[4*cc+2]);
                e.w = hq[cc].w * (1.f + 0.3f * d[4*cc+3]);
                enhU4[(size_t)ge * 4 + cc] = e;
                v[4*cc+0] = e.x; v[4*cc+1] = e.y; v[4*cc+2] = e.z; v[4*cc+3] = e.w;
            }
        } else {
#pragma unroll
            for (int b = 0; b < 16; b++) v[b] = 0.f;
        }
#pragma unroll
        for (int b = 0; b < 16; b++) {
            float s = v[b];
            for (int o = 32; o > 0; o >>= 1) s += __shfl_xor(s, o);
            if ((t & 63) == 0) atomicAdd(&hs[b], s);
        }
    }
    __syncthreads();
    if (t < 16) atomicAdd(&hsum[t], hs[t]);
}

// ---------------- follow (4 lanes per obj, float4 over b) + fused normacc(prev) ----------------
__global__ void __launch_bounds__(256) k_follow(const float4* __restrict__ srcU4,
        const float4* __restrict__ wrT4, const int* __restrict__ row,
        const int2* __restrict__ sr, float4* __restrict__ resOut4,
        unsigned* __restrict__ rmax, const float* __restrict__ rowsum,
        const float4* __restrict__ Un4, const float* __restrict__ nssum,
        const float4* __restrict__ nhc4, const float4* __restrict__ directT4,
        float4* __restrict__ escT4, int do_acc, int nscale) {
    __shared__ float4 wrs[kR * 4];
    __shared__ unsigned umax[16];
    int tid = threadIdx.x;
    if (tid < 16) umax[tid] = 0u;
    {
        const float4* rs4 = (const float4*)rowsum;
        for (int idx = tid; idx < kR * 4; idx += 256) {
            float4 s = rs4[idx & 3];
            float4 wv = wrT4[idx];
            wv.x *= (s.x > 0.f) ? 1.f / s.x : 1.f;
            wv.y *= (s.y > 0.f) ? 1.f / s.y : 1.f;
            wv.z *= (s.z > 0.f) ? 1.f / s.z : 1.f;
            wv.w *= (s.w > 0.f) ? 1.f / s.w : 1.f;
            wrs[idx] = wv;
        }
    }
    __syncthreads();
    int slot = (blockIdx.x * 256 + tid) >> 2;
    int bc = tid & 3;
    float4 a = make_float4(0.f, 0.f, 0.f, 0.f);
    if (slot < kE) {
        int f = slot * 4 + bc;
        if (do_acc) {
            float4 sv = ((const float4*)nssum)[bc];
            float4 si;
            si.x = (sv.x > 0.f) ? 1.f / sv.x : 1.f;
            si.y = (sv.y > 0.f) ? 1.f / sv.y : 1.f;
            si.z = (sv.z > 0.f) ? 1.f / sv.z : 1.f;
            si.w = (sv.w > 0.f) ? 1.f / sv.w : 1.f;
            float4 u = Un4[f];
            float4 hc = nhc4[bc];
            float4 e = escT4[f];
            if (nscale) {
                float4 d = directT4[f];
                e.x += hc.x * u.x * si.x * (1.f + 0.15f * d.x);
                e.y += hc.y * u.y * si.y * (1.f + 0.15f * d.y);
                e.z += hc.z * u.z * si.z * (1.f + 0.15f * d.z);
                e.w += hc.w * u.w * si.w * (1.f + 0.15f * d.w);
            } else {
                e.x += hc.x * u.x * si.x;
                e.y += hc.y * u.y * si.y;
                e.z += hc.z * u.z * si.z;
                e.w += hc.w * u.w * si.w;
            }
            escT4[f] = e;
        }
        int j0 = row[slot], j1 = row[slot + 1];
        float4 a2 = make_float4(0.f, 0.f, 0.f, 0.f);
        int j = j0;
        for (; j + 2 <= j1; j += 2) {
            int2 p0 = sr[j], p1 = sr[j + 1];
            float4 s0 = srcU4[p0.x * 4 + bc];
            float4 w0 = wrs[p0.y * 4 + bc];
            float4 s1 = srcU4[p1.x * 4 + bc];
            float4 w1 = wrs[p1.y * 4 + bc];
            a.x += s0.x * w0.x; a.y += s0.y * w0.y; a.z += s0.z * w0.z; a.w += s0.w * w0.w;
            a2.x += s1.x * w1.x; a2.y += s1.y * w1.y; a2.z += s1.z * w1.z; a2.w += s1.w * w1.w;
        }
        if (j < j1) {
            int2 p = sr[j];
            float4 s0 = srcU4[p.x * 4 + bc];
            float4 w0 = wrs[p.y * 4 + bc];
            a.x += s0.x * w0.x; a.y += s0.y * w0.y; a.z += s0.z * w0.z; a.w += s0.w * w0.w;
        }
        a.x = fminf(fmaxf(a.x + a2.x, 0.f), 1.f);
        a.y = fminf(fmaxf(a.y + a2.y, 0.f), 1.f);
        a.z = fminf(fmaxf(a.z + a2.z, 0.f), 1.f);
        a.w = fminf(fmaxf(a.w + a2.w, 0.f), 1.f);
        resOut4[f] = a;
    }
    // per-b max: reduce across slots in wave (lanes with same bc), then LDS, then global
    for (int o = 4; o < 64; o <<= 1) {
        a.x = fmaxf(a.x, __shfl_xor(a.x, o));
        a.y = fmaxf(a.y, __shfl_xor(a.y, o));
        a.z = fmaxf(a.z, __shfl_xor(a.z, o));
        a.w = fmaxf(a.w, __shfl_xor(a.w, o));
    }
    if ((tid & 63) < 4) {
        atomicMax(&umax[bc * 4 + 0], __float_as_uint(a.x));
        atomicMax(&umax[bc * 4 + 1], __float_as_uint(a.y));
        atomicMax(&umax[bc * 4 + 2], __float_as_uint(a.z));
        atomicMax(&umax[bc * 4 + 3], __float_as_uint(a.w));
    }
    __syncthreads();
    if (tid < 16) atomicMax(&rmax[tid], umax[tid]);
}

// ---------------- combine: /max, residual, *er, row sums (float4) ----------------
__global__ void __launch_bounds__(256) k_combine(float4* __restrict__ res4,
        const float4* __restrict__ uprev4, const float* __restrict__ ssum_prev,
        const float4* __restrict__ erT4, const unsigned* __restrict__ rmax16,
        float* __restrict__ ssum_out, int has_res) {
    __shared__ float ls[16];
    int tid = threadIdx.x;
    if (tid < 16) ls[tid] = 0.f;
    __syncthreads();
    int bc = tid & 3;
    uint4 rm = ((const uint4*)rmax16)[bc];
    float4 mi;
    { float m;
      m = __uint_as_float(rm.x); mi.x = (m > 0.f) ? 1.f / m : 1.f;
      m = __uint_as_float(rm.y); mi.y = (m > 0.f) ? 1.f / m : 1.f;
      m = __uint_as_float(rm.z); mi.z = (m > 0.f) ? 1.f / m : 1.f;
      m = __uint_as_float(rm.w); mi.w = (m > 0.f) ? 1.f / m : 1.f; }
    float4 si = make_float4(1.f, 1.f, 1.f, 1.f);
    if (has_res) {
        float4 s = ((const float4*)ssum_prev)[bc];
        si.x = (s.x > 0.f) ? 1.f / s.x : 1.f;
        si.y = (s.y > 0.f) ? 1.f / s.y : 1.f;
        si.z = (s.z > 0.f) ? 1.f / s.z : 1.f;
        si.w = (s.w > 0.f) ? 1.f / s.w : 1.f;
    }
    float4 su = make_float4(0.f, 0.f, 0.f, 0.f);
    int gsz = gridDim.x * 256;
    for (int f = blockIdx.x * 256 + tid; f < kEBq; f += gsz) {
        float4 v = res4[f];
        v.x *= mi.x; v.y *= mi.y; v.z *= mi.z; v.w *= mi.w;
        if (has_res) {
            float4 u = uprev4[f];
            v.x = 0.7f * v.x + 0.3f * u.x * si.x;
            v.y = 0.7f * v.y + 0.3f * u.y * si.y;
            v.z = 0.7f * v.z + 0.3f * u.z * si.z;
            v.w = 0.7f * v.w + 0.3f * u.w * si.w;
        }
        float4 er = erT4[f];
        v.x *= er.x; v.y *= er.y; v.z *= er.z; v.w *= er.w;
        res4[f] = v;
        su.x += v.x; su.y += v.y; su.z += v.z; su.w += v.w;
    }
    for (int o = 4; o < 64; o <<= 1) {
        su.x += __shfl_xor(su.x, o);
        su.y += __shfl_xor(su.y, o);
        su.z += __shfl_xor(su.z, o);
        su.w += __shfl_xor(su.w, o);
    }
    if ((tid & 63) < 4) {
        atomicAdd(&ls[bc * 4 + 0], su.x);
        atomicAdd(&ls[bc * 4 + 1], su.y);
        atomicAdd(&ls[bc * 4 + 2], su.z);
        atomicAdd(&ls[bc * 4 + 3], su.w);
    }
    __syncthreads();
    if (tid < 16) atomicAdd(&ssum_out[tid], ls[tid]);
}

// ---------------- final: out[b][e] = esc[e][b] + hc5[b]*U5[e][b]*sinv5[b] ----------------
__global__ void k_final(const float4* __restrict__ escT4, const float4* __restrict__ U4,
                        const float* __restrict__ ssum5, const float* __restrict__ hc5,
                        float* __restrict__ out) {
    int e = blockIdx.x * blockDim.x + threadIdx.x;
    if (e >= kE) return;
    float val[16];
#pragma unroll
    for (int c = 0; c < 4; c++) {
        float4 es = escT4[(size_t)e * 4 + c];
        float4 u  = U4[(size_t)e * 4 + c];
        float4 s  = ((const float4*)ssum5)[c];
        float4 h  = ((const float4*)hc5)[c];
        float4 si;
        si.x = (s.x > 0.f) ? 1.f / s.x : 1.f;
        si.y = (s.y > 0.f) ? 1.f / s.y : 1.f;
        si.z = (s.z > 0.f) ? 1.f / s.z : 1.f;
        si.w = (s.w > 0.f) ? 1.f / s.w : 1.f;
        val[4*c+0] = es.x + h.x * u.x * si.x;
        val[4*c+1] = es.y + h.y * u.y * si.y;
        val[4*c+2] = es.z + h.z * u.z * si.z;
        val[4*c+3] = es.w + h.w * u.w * si.w;
    }
#pragma unroll
    for (int b = 0; b < 16; b++) out[(size_t)b * kE + e] = val[b];
}

extern "C" void kernel_launch(void* const* d_in, const int* in_sizes, int n_in,
                              void* d_out, int out_size, void* d_ws, size_t ws_size,
                              hipStream_t stream) {
    const float* heads   = (const float*)d_in[0];
    const float* qemb    = (const float*)d_in[1];
    const float* qwh     = (const float*)d_in[2];
    const int*   amask   = (const int*)d_in[3];
    const float* erange  = (const float*)d_in[4];
    const int*   subj    = (const int*)d_in[5];
    const int*   rel     = (const int*)d_in[6];
    const int*   obj     = (const int*)d_in[7];
    const float* rimp    = (const float*)d_in[8];
    const float* emb     = (const float*)d_in[9];
    const float* mw      = (const float*)d_in[10];
    const float* mb      = (const float*)d_in[11];
    const float* sw      = (const float*)d_in[12];
    const float* sb      = (const float*)d_in[13];
    const float* rw      = (const float*)d_in[14];
    const float* rb      = (const float*)d_in[15];
    const float* hw      = (const float*)d_in[16];
    const float* hb      = (const float*)d_in[17];
    const float* temp    = (const float*)d_in[18];
    float* out = (float*)d_out;

    float* base = (float*)d_ws;
    float* directT = base;
    float* headsT  = directT + kEB;
    float* erT     = headsT + kEB;
    float* enhU    = erT + kEB;
    float* U0      = enhU + kEB;
    float* U1      = U0 + kEB;
    float* escT    = U1 + kEB;
    float* cq      = escT + kEB;                 // 7*16*768 = 86016
    float* wrT     = cq + (size_t)7 * 16 * kD;   // 6*200*16 = 19200
    float* hopL    = wrT + (size_t)6 * kR * 16;  // 96
    float* hsum    = hopL + 96;                  // 16
    float* ssum    = hsum + 16;                  // 96
    unsigned* rmax = (unsigned*)(ssum + 96);     // 96
    int* cnt       = (int*)(rmax + 96);          // E
    int* row       = cnt + kE;                   // E+1
    int* fill      = row + kE + 1;               // E
    int* bsum      = fill + kE;                  // 256
    int2* sr = (int2*)(((uintptr_t)(bsum + 256) + 255) & ~(uintptr_t)255);
    float* Ubuf[2] = {U0, U1};

    k_init<<<512, 256, 0, stream>>>(heads, erange, headsT, erT, escT, cnt, rmax, ssum, hsum);
    k_hist<<<512, 256, 0, stream>>>(obj, cnt);
    const int nb = (kE + 511) / 512;
    k_scan1<<<nb, 512, 0, stream>>>(cnt, row, bsum);
    k_scan2<<<1, 256, 0, stream>>>(bsum, nb);
    k_scan3<<<(kE + 255) / 256, 256, 0, stream>>>(cnt, row, fill, bsum);
    k_scatter<<<512, 256, 0, stream>>>(subj, rel, obj, fill, sr);

    k_dense<<<dim3(16, 7), 192, 0, stream>>>(qemb, mw, mb, sw, sb, cq);
    k_hop<<<dim3(2, 16), 192, 0, stream>>>(qemb, hw, hb, hopL);
    k_ctx<<<dim3(6, 16), 256, 0, stream>>>(cq, qwh, amask, rw, rb, rimp, temp, wrT);

    k_direct<<<782, 256, 0, stream>>>((const float4*)emb, (const float4*)cq,
                                      (const float4*)headsT, (float4*)directT,
                                      (float4*)enhU, hsum);

    for (int i = 0; i < 6; i++) {
        int w = i / 3, t = i % 3;
        const float* srcU = (t == 0) ? enhU : Ubuf[(i - 1) & 1];
        const float* rowsum = (t == 0) ? hsum : ssum + (i - 1) * 16;
        int do_acc = (i > 0);
        const float* Un = do_acc ? Ubuf[(i - 1) & 1] : enhU;       // dummy when !do_acc
        const float* nss = do_acc ? ssum + (i - 1) * 16 : hsum;
        const float* nhc = hopL + (do_acc ? (i - 1) * 16 : 0);
        int nscale = do_acc ? ((i - 1) < 3 ? 1 : 0) : 0;
        k_follow<<<1563, 256, 0, stream>>>((const float4*)srcU,
                (const float4*)(wrT + (size_t)i * kR * 16), row, sr,
                (float4*)Ubuf[i & 1], rmax + i * 16, rowsum,
                (const float4*)Un, nss, (const float4*)nhc,
                (const float4*)directT, (float4*)escT, do_acc, nscale);
        k_combine<<<1024, 256, 0, stream>>>((float4*)Ubuf[i & 1],
                (const float4*)(t > 0 ? Ubuf[(i - 1) & 1] : enhU),
                t > 0 ? ssum + (i - 1) * 16 : hsum,
                (const float4*)erT, rmax + i * 16, ssum + i * 16, t > 0 ? 1 : 0);
        (void)w;
    }
    k_final<<<(kE + 255) / 256, 256, 0, stream>>>((const float4*)escT,
            (const float4*)Ubuf[1], ssum + 80, hopL + 80, out);
}